// Round 6
// baseline (1275.078 us; speedup 1.0000x reference)
//
#include <hip/hip_runtime.h>

#define RR 64
#define TT 256
#define NN 1024
#define CC 32            // superstep length == extra skew per wave boundary
#define RB 128           // LDS ring depth (slots)
#define NSTEP 51         // ceil((2*(TT-1) + 3*CC + NN) / CC) : max w = 1629 < 51*32
#define C0SZ 1648        // shifted+padded comm0 LDS copy (per run-group)

typedef float v2f __attribute__((ext_vector_type(2)));

// TWO runs per block (512 threads): group g = tid>>8 owns run blockIdx*2+g.
// Rationale (round-4 A/B): at 1 wave/SIMD the kernel is LATENCY-bound —
// every instruction costs ~its dep latency (~6cy), not issue rate (~2cy);
// adding VALU ops (magic rcp) cost exactly latency*ops, removing trans ops
// saved nothing. Packing 2 runs/block gives 2 waves/SIMD: independent
// streams fill each other's dependency bubbles. Compute path is the exact
// round-2 version (hw v_rcp_f32; magic-NR variant failed accuracy at 2 steps
// and regressed speed at 3 — the 1632-step recurrence amplifies rel err ~1e5x,
// and extra VALU ops cost full latency here).
//
// Per run: thread t owns timestep t. Wavefront w processes cell
// (t, i = w - skew(t)), skew(t) = 2t + (t/64)*CC. Intra-wave neighbor handoff
// via DPP wave_shr:1; cross-wave handoff via LDS ring (batched b128 reads);
// sensing data register-prefetched one superstep ahead behind an asm fence.
extern "C" __global__ __launch_bounds__(512, 1)
void comnet_kernel(const float* __restrict__ runs,   // (R,T,N,2)
                   const float* __restrict__ comm0,  // (R,N)
                   const float* __restrict__ w1,     // (10,4)
                   const float* __restrict__ b1,     // (10)
                   const float* __restrict__ w2,     // (2,10)
                   const float* __restrict__ b2,     // (2)
                   float* __restrict__ out)          // (R,T,N)
{
    const int g    = threadIdx.x >> 8;         // run-group within block (0/1)
    const int t    = threadIdx.x & 255;        // timestep within run
    const int r    = blockIdx.x * 2 + g;
    const int lane = t & 63;
    const int wv   = t >> 6;                   // wave-row within group (0..3)
    const int skew = 2 * t + wv * CC;          // even for all t

    __shared__ __attribute__((aligned(16))) float s_c0[2][C0SZ];
    __shared__ __attribute__((aligned(16))) float s_ring[2][4][RB];

    // Shifted comm0 copy: s_c0[g][k+3] = comm0[r][k]; zeros elsewhere. +3 shift
    // makes the per-superstep window s_c0[g][wbase+4 .. wbase+35] 16B-aligned.
    for (int k = t; k < C0SZ; k += 256) {
        float v = 0.0f;
        if (k >= 3 && k < 3 + NN) v = comm0[r * NN + (k - 3)];
        s_c0[g][k] = v;
    }

    // Folded tanh: tanh(z) = 1 - 2*s, s = rcp(1 + exp2(Kc*z)), Kc = 2*log2(e)
    const float Kc = 2.885390081777927f;
    v2f Ax[5], Ay[5], Al[5], Ar[5], Bz[5], M0[5], M1[5];
    float C0 = b2[0], C1 = b2[1];
#pragma unroll
    for (int j = 0; j < 5; ++j) {
        const int k0 = 2 * j, k1 = 2 * j + 1;
        Ax[j] = v2f{Kc * w1[k0 * 4 + 0], Kc * w1[k1 * 4 + 0]};
        Ay[j] = v2f{Kc * w1[k0 * 4 + 1], Kc * w1[k1 * 4 + 1]};
        Al[j] = v2f{Kc * w1[k0 * 4 + 2], Kc * w1[k1 * 4 + 2]};
        Ar[j] = v2f{Kc * w1[k0 * 4 + 3], Kc * w1[k1 * 4 + 3]};
        Bz[j] = v2f{Kc * b1[k0], Kc * b1[k1]};
        const float u00 = w2[k0],      u01 = w2[k1];
        const float u10 = w2[10 + k0], u11 = w2[10 + k1];
        C0 += u00 + u01;
        C1 += u10 + u11;
        M0[j] = v2f{-2.0f * u00, -2.0f * u01};
        M1[j] = v2f{-2.0f * u10, -2.0f * u11};
    }

    __syncthreads();

    const float4* xp4 = (const float4*)(runs + (size_t)(r * TT + t) * NN * 2);
    float*        opb = out + (size_t)(r * TT + t) * NN - skew;  // skew folded in

    const bool l0  = (lane == 0);
    const bool l63 = (lane == 63);
    float c_prev = 0.0f;

    // DPP wave_shr:1 — lane n gets lane n-1's value (lane 0 keeps old; patched
    // from ring). Executed only at full exec (outside act-guarded regions).
    auto shr1 = [](float x) {
        const int xi = __float_as_int(x);
        return __int_as_float(__builtin_amdgcn_update_dpp(xi, xi, 0x138, 0xF, 0xF, false));
    };

    // Packed MLP, hw v_rcp_f32. zb[j] = Ax*x + Ay*y + Bz precomputed
    // (recurrence-independent). Split accumulators shorten the serial tail.
    auto mlp = [&](const v2f* zb, float left, float right, float& o0) {
        const v2f lv = {left, left}, rv = {right, right};
        v2f a0a = {0.f, 0.f}, a0b = {0.f, 0.f}, a1a = {0.f, 0.f}, a1b = {0.f, 0.f};
#pragma unroll
        for (int j = 0; j < 5; ++j) {
            v2f z = __builtin_elementwise_fma(
                        Al[j], lv, __builtin_elementwise_fma(Ar[j], rv, zb[j]));
            v2f e;
            e.x = __builtin_amdgcn_exp2f(z.x);
            e.y = __builtin_amdgcn_exp2f(z.y);
            const v2f d = e + 1.0f;
            v2f sg;
            sg.x = __builtin_amdgcn_rcpf(d.x);
            sg.y = __builtin_amdgcn_rcpf(d.y);
            if (j < 3) {
                a0a = __builtin_elementwise_fma(M0[j], sg, a0a);
                a1a = __builtin_elementwise_fma(M1[j], sg, a1a);
            } else {
                a0b = __builtin_elementwise_fma(M0[j], sg, a0b);
                a1b = __builtin_elementwise_fma(M1[j], sg, a1b);
            }
        }
        const v2f s0 = a0a + a0b, s1 = a1a + a1b;
        o0     = C0 + (s0.x + s0.y);
        c_prev = C1 + (s1.x + s1.y);
    };

    // Prologue: sensing data for superstep 0 (clamped; guarded by act at use).
    float4 qc[16];
#pragma unroll
    for (int u = 0; u < 16; ++u) {
        const int idx = min(max(2 * u - skew, 0), NN - 2);
        qc[u] = xp4[idx >> 1];
    }

#pragma unroll 1
    for (int s = 0; s < NSTEP; ++s) {
        const int wbase = s * CC;

        // A: batch lane-0 neighbor values (8 aligned b128, uniform addr).
        const float4* rbase = (wv == 0)
            ? (const float4*)(s_c0[g] + (wbase + 4))
            : (const float4*)(s_ring[g][wv - 1] + (wbase & (RB - 1)));
        float4 rv4[8];
#pragma unroll
        for (int m = 0; m < 8; ++m) rv4[m] = rbase[m];

        // B: issue next superstep's 16 sensing loads.
        float4 qn[16];
        const int i0n = wbase + CC - skew;
#pragma unroll
        for (int u = 0; u < 16; ++u) {
            const int idx = min(max(i0n + 2 * u, 0), NN - 2);
            qn[u] = xp4[idx >> 1];
        }

        // Fence: loads above may NOT sink below this point; first use is after
        // the compute section (one superstep of latency slack).
        asm volatile("" ::: "memory");

        const int woff = (wbase + 33) & (RB - 1);  // ring slot(w) = (w+33)&127
        float* wrow = s_ring[g][wv];
        float* ops  = opb + wbase;                 // stores use imm offsets

        // C: 32 cells (16 pairs), fully unrolled for static register indexing.
#pragma unroll
        for (int u = 0; u < 16; ++u) {
            const int  i0  = wbase + 2 * u - skew;
            const bool act = (unsigned)i0 < NN;    // covers both cells (i0 even)
            const float rvA = (u & 1) ? rv4[u >> 1].z : rv4[u >> 1].x;
            const float rvB = (u & 1) ? rv4[u >> 1].w : rv4[u >> 1].y;

            float o0a = 0.0f, o0b, rA = 0.0f;
            v2f zb1[5];

            // cell 1: i0 even -> never right boundary; left boundary possible
            float nb = shr1(c_prev);
            nb = l0 ? rvA : nb;
            if (act) {
                v2f zb0[5];
                const v2f xv0 = {qc[u].x, qc[u].x}, yv0 = {qc[u].y, qc[u].y};
                const v2f xv1 = {qc[u].z, qc[u].z}, yv1 = {qc[u].w, qc[u].w};
#pragma unroll
                for (int j = 0; j < 5; ++j) {
                    zb0[j] = __builtin_elementwise_fma(
                                Ay[j], yv0, __builtin_elementwise_fma(Ax[j], xv0, Bz[j]));
                    zb1[j] = __builtin_elementwise_fma(
                                Ay[j], yv1, __builtin_elementwise_fma(Ax[j], xv1, Bz[j]));
                }
                const float left = (i0 == 0) ? 0.0f : c_prev;
                mlp(zb0, left, nb, o0a);
                rA = c_prev;
            }

            // cell 2: i0+1 odd -> never left boundary; right boundary possible
            float nb2 = shr1(c_prev);
            nb2 = l0 ? rvB : nb2;
            if (act) {
                const float right = (i0 == NN - 2) ? 0.0f : nb2;
                mlp(zb1, c_prev, right, o0b);
                *(float2*)(ops + 2 * u) = make_float2(o0a, o0b);
            }

            // Ring writes: only active lane-63 cells are ever consumed.
            if (act & l63) {
                wrow[(woff + 2 * u)     & (RB - 1)] = rA;
                wrow[(woff + 2 * u + 1) & (RB - 1)] = c_prev;
            }
        }

        // D: roll prefetch buffer (vmcnt waits land here, right at the barrier).
#pragma unroll
        for (int u = 0; u < 16; ++u) qc[u] = qn[u];

        __syncthreads();
    }
}

extern "C" void kernel_launch(void* const* d_in, const int* in_sizes, int n_in,
                              void* d_out, int out_size, void* d_ws, size_t ws_size,
                              hipStream_t stream) {
    const float* runs  = (const float*)d_in[0];
    const float* comm0 = (const float*)d_in[1];
    const float* w1    = (const float*)d_in[2];
    const float* b1    = (const float*)d_in[3];
    const float* w2    = (const float*)d_in[4];
    const float* b2    = (const float*)d_in[5];
    float* out = (float*)d_out;
    (void)in_sizes; (void)n_in; (void)out_size; (void)d_ws; (void)ws_size;

    comnet_kernel<<<dim3(RR / 2), dim3(512), 0, stream>>>(runs, comm0, w1, b1, w2, b2, out);
}

// Round 8
// 668.466 us; speedup vs baseline: 1.9075x; 1.9075x over previous
//
#include <hip/hip_runtime.h>

#define RR 64
#define TT 256
#define NN 1024
#define CC 32            // superstep length == extra skew per wave boundary
#define RB 128           // LDS ring depth (slots)
#define NSTEP 51         // ceil((2*(TT-1) + 3*CC + NN) / CC) : max w = 1629 < 51*32
#define C0SZ 1648        // shifted+padded comm0 LDS copy

typedef float v2f __attribute__((ext_vector_type(2)));

// One block per run (64 x 256; round-6 proved 2 waves/SIMD serialize here).
// Thread t owns timestep t. Wavefront w processes cell (t, i = w - skew(t)),
// skew(t) = 2t + (t/64)*CC. Intra-wave neighbor handoff via DPP wave_shr:1;
// cross-wave handoff via LDS ring (batched b128 reads); sensing data
// register-prefetched one superstep ahead behind an asm fence.
//
// Branchless cell bodies (round-7 experiment) + round-8 purity fixes:
// round 7 PASSED its first launch but diverged on replays — it read stale
// LDS (uninitialized s_ring) whose content differs between launch 1 (fresh)
// and later launches (our own leftovers). Fixes: (1) s_ring zero-init, so
// every LDS read is this-launch data or deterministic 0; (2) nb sanitized to
// 0 for inactive lanes, so garbage can never enter computed chains through
// any path. Kernel is now a pure function of inputs -> replay-consistent,
// and active-lane dataflow is bit-identical to the passing round-2 kernel.
extern "C" __global__ __launch_bounds__(256, 1)
void comnet_kernel(const float* __restrict__ runs,   // (R,T,N,2)
                   const float* __restrict__ comm0,  // (R,N)
                   const float* __restrict__ w1,     // (10,4)
                   const float* __restrict__ b1,     // (10)
                   const float* __restrict__ w2,     // (2,10)
                   const float* __restrict__ b2,     // (2)
                   float* __restrict__ out)          // (R,T,N)
{
    const int r    = blockIdx.x;
    const int t    = threadIdx.x;
    const int lane = t & 63;
    const int wv   = t >> 6;
    const int skew = 2 * t + wv * CC;          // even for all t

    __shared__ __attribute__((aligned(16))) float s_c0[C0SZ];
    __shared__ __attribute__((aligned(16))) float s_ring[4][RB];

    // Zero the ring: purity across graph replays (see header comment).
    for (int k = t; k < 4 * RB; k += 256) ((float*)s_ring)[k] = 0.0f;

    // Shifted comm0 copy: s_c0[k+3] = comm0[k]; zeros elsewhere. +3 shift makes
    // the per-superstep window s_c0[wbase+4 .. wbase+35] 16B-aligned.
    for (int k = t; k < C0SZ; k += 256) {
        float v = 0.0f;
        if (k >= 3 && k < 3 + NN) v = comm0[r * NN + (k - 3)];
        s_c0[k] = v;
    }

    // Folded tanh: tanh(z) = 1 - 2*s, s = rcp(1 + exp2(Kc*z)), Kc = 2*log2(e)
    const float Kc = 2.885390081777927f;
    v2f Ax[5], Ay[5], Al[5], Ar[5], Bz[5], M0[5], M1[5];
    float C0 = b2[0], C1 = b2[1];
#pragma unroll
    for (int j = 0; j < 5; ++j) {
        const int k0 = 2 * j, k1 = 2 * j + 1;
        Ax[j] = v2f{Kc * w1[k0 * 4 + 0], Kc * w1[k1 * 4 + 0]};
        Ay[j] = v2f{Kc * w1[k0 * 4 + 1], Kc * w1[k1 * 4 + 1]};
        Al[j] = v2f{Kc * w1[k0 * 4 + 2], Kc * w1[k1 * 4 + 2]};
        Ar[j] = v2f{Kc * w1[k0 * 4 + 3], Kc * w1[k1 * 4 + 3]};
        Bz[j] = v2f{Kc * b1[k0], Kc * b1[k1]};
        const float u00 = w2[k0],      u01 = w2[k1];
        const float u10 = w2[10 + k0], u11 = w2[10 + k1];
        C0 += u00 + u01;
        C1 += u10 + u11;
        M0[j] = v2f{-2.0f * u00, -2.0f * u01};
        M1[j] = v2f{-2.0f * u10, -2.0f * u11};
    }

    __syncthreads();

    const float4* xp4 = (const float4*)(runs + (size_t)(r * TT + t) * NN * 2);
    float*        opb = out + (size_t)(r * TT + t) * NN - skew;  // skew folded in

    const bool l0  = (lane == 0);
    const bool l63 = (lane == 63);
    float c_prev = 0.0f;

    // DPP wave_shr:1 — lane n gets lane n-1's value (lane 0 keeps old; patched
    // from ring). Always executed at full exec (no divergent regions left).
    auto shr1 = [](float x) {
        const int xi = __float_as_int(x);
        return __int_as_float(__builtin_amdgcn_update_dpp(xi, xi, 0x138, 0xF, 0xF, false));
    };

    // Packed MLP, hw v_rcp_f32, pure. zb[j] precomputed (recurrence-
    // independent). Split accumulators shorten the serial tail.
    auto mlp = [&](const v2f* zb, float left, float right, float& o0, float& c_out) {
        const v2f lv = {left, left}, rv = {right, right};
        v2f a0a = {0.f, 0.f}, a0b = {0.f, 0.f}, a1a = {0.f, 0.f}, a1b = {0.f, 0.f};
#pragma unroll
        for (int j = 0; j < 5; ++j) {
            v2f z = __builtin_elementwise_fma(
                        Al[j], lv, __builtin_elementwise_fma(Ar[j], rv, zb[j]));
            v2f e;
            e.x = __builtin_amdgcn_exp2f(z.x);
            e.y = __builtin_amdgcn_exp2f(z.y);
            const v2f d = e + 1.0f;
            v2f sg;
            sg.x = __builtin_amdgcn_rcpf(d.x);
            sg.y = __builtin_amdgcn_rcpf(d.y);
            if (j < 3) {
                a0a = __builtin_elementwise_fma(M0[j], sg, a0a);
                a1a = __builtin_elementwise_fma(M1[j], sg, a1a);
            } else {
                a0b = __builtin_elementwise_fma(M0[j], sg, a0b);
                a1b = __builtin_elementwise_fma(M1[j], sg, a1b);
            }
        }
        const v2f s0 = a0a + a0b, s1 = a1a + a1b;
        o0    = C0 + (s0.x + s0.y);
        c_out = C1 + (s1.x + s1.y);
    };

    // Prologue: sensing data for superstep 0 (clamped; always finite).
    float4 qc[16];
#pragma unroll
    for (int u = 0; u < 16; ++u) {
        const int idx = min(max(2 * u - skew, 0), NN - 2);
        qc[u] = xp4[idx >> 1];
    }

#pragma unroll 1
    for (int s = 0; s < NSTEP; ++s) {
        const int wbase = s * CC;

        // A: batch lane-0 neighbor values (8 aligned b128, uniform addr).
        const float4* rbase = (wv == 0)
            ? (const float4*)(s_c0 + (wbase + 4))
            : (const float4*)(s_ring[wv - 1] + (wbase & (RB - 1)));
        float4 rv4[8];
#pragma unroll
        for (int m = 0; m < 8; ++m) rv4[m] = rbase[m];

        // B: issue next superstep's 16 sensing loads.
        float4 qn[16];
        const int i0n = wbase + CC - skew;
#pragma unroll
        for (int u = 0; u < 16; ++u) {
            const int idx = min(max(i0n + 2 * u, 0), NN - 2);
            qn[u] = xp4[idx >> 1];
        }

        // Fence: loads above may NOT sink below this point; first use is after
        // the compute section (one superstep of latency slack).
        asm volatile("" ::: "memory");

        const int woff = (wbase + 33) & (RB - 1);  // ring slot(w) = (w+33)&127
        float* wrow = s_ring[wv];
        float* ops  = opb + wbase;                 // stores use imm offsets

        // C: 32 cells (16 pairs), fully unrolled, straight-line per pair.
#pragma unroll
        for (int u = 0; u < 16; ++u) {
            const int  i0  = wbase + 2 * u - skew;
            const bool act = (unsigned)i0 < NN;    // per-lane; selects only
            const float rvA = (u & 1) ? rv4[u >> 1].z : rv4[u >> 1].x;
            const float rvB = (u & 1) ? rv4[u >> 1].w : rv4[u >> 1].y;

            // zb for both cells (pk, recurrence-independent)
            v2f zb0[5], zb1[5];
            const v2f xv0 = {qc[u].x, qc[u].x}, yv0 = {qc[u].y, qc[u].y};
            const v2f xv1 = {qc[u].z, qc[u].z}, yv1 = {qc[u].w, qc[u].w};
#pragma unroll
            for (int j = 0; j < 5; ++j) {
                zb0[j] = __builtin_elementwise_fma(
                            Ay[j], yv0, __builtin_elementwise_fma(Ax[j], xv0, Bz[j]));
                zb1[j] = __builtin_elementwise_fma(
                            Ay[j], yv1, __builtin_elementwise_fma(Ax[j], xv1, Bz[j]));
            }

            // cell 1: i0 even -> never right boundary; left boundary possible
            float nb = shr1(c_prev);
            nb = l0 ? rvA : nb;
            nb = act ? nb : 0.0f;                  // sanitize: no foreign bits
            const float left1 = (i0 == 0) ? 0.0f : c_prev;
            float o0a, c1;
            mlp(zb0, left1, nb, o0a, c1);
            c_prev = act ? c1 : c_prev;            // hold last valid value
            if (l63) wrow[(woff + 2 * u) & (RB - 1)] = c_prev;

            // cell 2: i0+1 odd -> never left boundary; right boundary possible
            float nb2 = shr1(c_prev);
            nb2 = l0 ? rvB : nb2;
            nb2 = act ? nb2 : 0.0f;                // sanitize
            const float right2 = (i0 == NN - 2) ? 0.0f : nb2;
            float o0b, c2;
            mlp(zb1, c_prev, right2, o0b, c2);
            c_prev = act ? c2 : c_prev;
            if (l63) wrow[(woff + 2 * u + 1) & (RB - 1)] = c_prev;

            // only the 8B store is exec-guarded
            if (act) *(float2*)(ops + 2 * u) = make_float2(o0a, o0b);
        }

        // D: roll prefetch buffer (vmcnt waits land here, right at the barrier).
#pragma unroll
        for (int u = 0; u < 16; ++u) qc[u] = qn[u];

        __syncthreads();
    }
}

extern "C" void kernel_launch(void* const* d_in, const int* in_sizes, int n_in,
                              void* d_out, int out_size, void* d_ws, size_t ws_size,
                              hipStream_t stream) {
    const float* runs  = (const float*)d_in[0];
    const float* comm0 = (const float*)d_in[1];
    const float* w1    = (const float*)d_in[2];
    const float* b1    = (const float*)d_in[3];
    const float* w2    = (const float*)d_in[4];
    const float* b2    = (const float*)d_in[5];
    float* out = (float*)d_out;
    (void)in_sizes; (void)n_in; (void)out_size; (void)d_ws; (void)ws_size;

    comnet_kernel<<<dim3(RR), dim3(256), 0, stream>>>(runs, comm0, w1, b1, w2, b2, out);
}